// Round 5
// baseline (13304.927 us; speedup 1.0000x reference)
//
#include <hip/hip_runtime.h>
#include <hip/hip_bf16.h>

typedef __hip_bfloat16 bf16;

__device__ __forceinline__ float to_f(float x) { return x; }
__device__ __forceinline__ float to_f(bf16 x) { return __bfloat162float(x); }

// Dual-dtype parameter load: harness may pass reference params as f32 or bf16.
__device__ __forceinline__ float ldp(const void* p, size_t i, bool f32) {
  return f32 ? ((const float*)p)[i]
             : __bfloat162float(((const bf16*)p)[i]);
}

// Probe a buffer known to hold ~N(0,0.05^2) values. If it's f32 data, its
// low-half u16s decode (as bf16) to wild exponents ~88% of the time; if bf16
// data, essentially all u16s decode to plausible magnitudes. flag=1 -> f32.
__global__ void detect_kernel(const void* __restrict__ probe,
                              unsigned* __restrict__ flag) {
  __shared__ int sbad;
  if (threadIdx.x == 0) sbad = 0;
  __syncthreads();
  const unsigned short* u = (const unsigned short*)probe;
  int bad = 0;
  for (int i = threadIdx.x; i < 2048; i += 256) {
    unsigned short w = u[i];
    unsigned e = (w >> 7) & 0xFFu;
    bool plaus = (w == 0) || (w == 0x8000u) || (e >= 0x60u && e <= 0x7Eu);
    if (!plaus) bad++;
  }
  atomicAdd(&sbad, bad);
  __syncthreads();
  if (threadIdx.x == 0) *flag = (sbad > 100) ? 1u : 0u;
}

#define BM 64
#define BN 64
#define BKK 16

// C(M,N) = act( A(M,K) @ W(K,N) + bias(N) )
// A: TA* with row stride lda (workspace tensor), or GATHER: param emb rows
// rowidx[m] (dual-dtype). W/bias are params (dual-dtype). OUT_BF16: write
// bf16 else f32. ACT: 1 = tanh. M%64==0, N%64==0, K guarded.
template <typename TA, bool OUT_BF16, int ACT, bool GATHER>
__global__ __launch_bounds__(256) void gemm_kernel(
    const void* __restrict__ A, int lda, const int* __restrict__ rowidx,
    const void* __restrict__ W, const void* __restrict__ bias,
    void* __restrict__ Cv, int M, int K, int N,
    const unsigned* __restrict__ dflag) {
  __shared__ float As[BKK][BM + 4];
  __shared__ float Ws[BKK][BN];
  __shared__ int rows[BM];
  const bool isf32 = (*dflag != 0u);
  const int tid = threadIdx.x;
  const int tx = tid & 15, ty = tid >> 4;
  const int m0 = blockIdx.y * BM, n0 = blockIdx.x * BN;

  if (GATHER) {
    if (tid < BM) rows[tid] = rowidx[m0 + tid];
    __syncthreads();
  }

  float acc[4][4];
#pragma unroll
  for (int i = 0; i < 4; i++)
#pragma unroll
    for (int j = 0; j < 4; j++) acc[i][j] = 0.f;

  for (int k0 = 0; k0 < K; k0 += BKK) {
#pragma unroll
    for (int i = 0; i < 4; i++) {
      int li = tid + i * 256;
      int k = li & 15, m = li >> 4;
      float v = 0.f;
      if (k0 + k < K) {
        if (GATHER)
          v = ldp(A, (size_t)rows[m] * lda + k0 + k, isf32);
        else
          v = to_f(((const TA*)A)[(size_t)(m0 + m) * lda + k0 + k]);
      }
      As[k][m] = v;
    }
#pragma unroll
    for (int i = 0; i < 4; i++) {
      int li = tid + i * 256;
      int n = li & 63, k = li >> 6;
      float v = 0.f;
      if (k0 + k < K) v = ldp(W, (size_t)(k0 + k) * N + n0 + n, isf32);
      Ws[k][n] = v;
    }
    __syncthreads();
#pragma unroll
    for (int kk = 0; kk < BKK; kk++) {
      float a[4], b[4];
#pragma unroll
      for (int i = 0; i < 4; i++) a[i] = As[kk][ty * 4 + i];
#pragma unroll
      for (int j = 0; j < 4; j++) b[j] = Ws[kk][tx * 4 + j];
#pragma unroll
      for (int i = 0; i < 4; i++)
#pragma unroll
        for (int j = 0; j < 4; j++) acc[i][j] += a[i] * b[j];
    }
    __syncthreads();
  }

#pragma unroll
  for (int i = 0; i < 4; i++) {
    int m = m0 + ty * 4 + i;
#pragma unroll
    for (int j = 0; j < 4; j++) {
      int n = n0 + tx * 4 + j;
      float v = acc[i][j];
      if (bias) v += ldp(bias, n, isf32);
      if (ACT == 1) v = tanhf(v);
      if (OUT_BF16)
        ((bf16*)Cv)[(size_t)m * N + n] = __float2bfloat16(v);
      else
        ((float*)Cv)[(size_t)m * N + n] = v;
    }
  }
}

template <typename TA, bool OB, int ACT>
static void gemm(const TA* A, int lda, const void* W, const void* bias,
                 void* C, int M, int K, int N, const unsigned* dflag,
                 hipStream_t s) {
  dim3 g(N / BN, M / BM);
  gemm_kernel<TA, OB, ACT, false><<<g, 256, 0, s>>>(A, lda, nullptr, W, bias,
                                                    C, M, K, N, dflag);
}

static void gemm_gather(const void* emb, int lda, const int* rowidx,
                        const void* W, const void* bias, void* C, int M, int K,
                        int N, const unsigned* dflag, hipStream_t s) {
  dim3 g(N / BN, M / BM);
  gemm_kernel<bf16, false, 0, true><<<g, 256, 0, s>>>(emb, lda, rowidx, W,
                                                      bias, C, M, K, N, dflag);
}

// writes dec embedding into xg[:, 0:300] and cat2[:, 768:1068]
__global__ void embed_dec_kernel(const int* __restrict__ trg_t,
                                 const void* __restrict__ emb,
                                 float* __restrict__ xg,
                                 float* __restrict__ cat2,
                                 const unsigned* __restrict__ dflag) {
  const bool isf32 = (*dflag != 0u);
  int idx = blockIdx.x * 256 + threadIdx.x;  // B*E exact
  int e = idx % 300;
  int b = idx / 300;
  float v = ldp(emb, (size_t)trg_t[b] * 300 + e, isf32);
  xg[(size_t)b * 812 + e] = v;
  cat2[(size_t)b * 1068 + 768 + e] = v;
}

// GRU cell elementwise: h (row stride ldh) updated in place. Optional mirrors
// of new h: aux_bf16[b*stride_b+i], aux_f32[b*stride_f+i].
__global__ __launch_bounds__(256) void gru_cell_kernel(
    const float* __restrict__ gi, const float* __restrict__ gh,
    float* __restrict__ h, int ldh, bf16* __restrict__ aux_bf16, int stride_b,
    float* __restrict__ aux_f32, int stride_f) {
  int b = blockIdx.x, i = threadIdx.x;
  const float* gib = gi + (size_t)b * 768;
  const float* ghb = gh + (size_t)b * 768;
  float ir = gib[i], iz = gib[256 + i], in_ = gib[512 + i];
  float hr = ghb[i], hz = ghb[256 + i], hn = ghb[512 + i];
  float hv = h[(size_t)b * ldh + i];
  float r = 1.f / (1.f + expf(-(ir + hr)));
  float z = 1.f / (1.f + expf(-(iz + hz)));
  float n = tanhf(in_ + r * hn);
  float out = (1.f - z) * n + z * hv;
  h[(size_t)b * ldh + i] = out;
  if (aux_bf16) aux_bf16[(size_t)b * stride_b + i] = __float2bfloat16(out);
  if (aux_f32) aux_f32[(size_t)b * stride_f + i] = out;
}

// Per-block b: score[s] = sum_i v[i]*tanh(hWh[b,i] + proj[b,s,i]); softmax
// over s; weighted[d] = sum_s a[s]*bse[b,s,d]; writes xg[:,300:812] and
// cat2[:,256:768]. proj already includes attn_b (folded into GEMM bias).
__global__ __launch_bounds__(256) void attn_kernel(
    const float* __restrict__ hWh, const bf16* __restrict__ proj,
    const bf16* __restrict__ bse, const void* __restrict__ v,
    float* __restrict__ xg, float* __restrict__ cat2,
    const unsigned* __restrict__ dflag) {
  const bool isf32 = (*dflag != 0u);
  int b = blockIdx.x, tid = threadIdx.x;
  int wave = tid >> 6, lane = tid & 63;
  __shared__ float partial[24][4];
  __shared__ float aw[24];
  float vh = hWh[(size_t)b * 256 + tid];
  float vv = ldp(v, tid, isf32);
  const bf16* pb = proj + (size_t)b * 24 * 256;
#pragma unroll 4
  for (int s = 0; s < 24; s++) {
    float e = tanhf(vh + __bfloat162float(pb[s * 256 + tid]));
    float t = vv * e;
#pragma unroll
    for (int off = 32; off > 0; off >>= 1) t += __shfl_down(t, off, 64);
    if (lane == 0) partial[s][wave] = t;
  }
  __syncthreads();
  if (tid == 0) {
    float sc[24];
    float mx = -1e30f;
    for (int s = 0; s < 24; s++) {
      float xv = partial[s][0] + partial[s][1] + partial[s][2] + partial[s][3];
      sc[s] = xv;
      mx = fmaxf(mx, xv);
    }
    float sum = 0.f;
    for (int s = 0; s < 24; s++) {
      sc[s] = expf(sc[s] - mx);
      sum += sc[s];
    }
    float inv = 1.f / sum;
    for (int s = 0; s < 24; s++) aw[s] = sc[s] * inv;
  }
  __syncthreads();
  const bf16* eb = bse + (size_t)b * 24 * 512;
  float w0 = 0.f, w1 = 0.f;
#pragma unroll 4
  for (int s = 0; s < 24; s++) {
    float a = aw[s];
    w0 += a * __bfloat162float(eb[s * 512 + tid]);
    w1 += a * __bfloat162float(eb[s * 512 + 256 + tid]);
  }
  xg[(size_t)b * 812 + 300 + tid] = w0;
  xg[(size_t)b * 812 + 300 + 256 + tid] = w1;
  cat2[(size_t)b * 1068 + 256 + tid] = w0;
  cat2[(size_t)b * 1068 + 256 + 256 + tid] = w1;
}

// Diagnostic: workspace too small -> flood 123.0 (absmax ~1.2e2 tells us).
__global__ void sentinel_kernel(float* out, int n) {
  int i = blockIdx.x * 256 + threadIdx.x;
  if (i < n) out[i] = 123.0f;
}

extern "C" void kernel_launch(void* const* d_in, const int* in_sizes, int n_in,
                              void* d_out, int out_size, void* d_ws,
                              size_t ws_size, hipStream_t stream) {
  const int B = 2048, S = 24, T = 25, H = 256, E = 300, VOUT = 128;
  const int* src = (const int*)d_in[0];
  const int* trg = (const int*)d_in[1];
  const void* enc_emb = d_in[2];
  const void* enc_Wih_f = d_in[3];
  const void* enc_Whh_f = d_in[4];
  const void* enc_bih_f = d_in[5];
  const void* enc_bhh_f = d_in[6];
  const void* enc_Wih_b = d_in[7];
  const void* enc_Whh_b = d_in[8];
  const void* enc_bih_b = d_in[9];
  const void* enc_bhh_b = d_in[10];
  const void* enc_fcW = d_in[11];
  const void* enc_fcb = d_in[12];
  const void* attn_Wh = d_in[13];
  const void* attn_We = d_in[14];
  const void* attn_b = d_in[15];
  const void* attn_v = d_in[16];
  const void* dec_emb = d_in[17];
  const void* dec_Wih = d_in[18];
  const void* dec_Whh = d_in[19];
  const void* dec_bih = d_in[20];
  const void* dec_bhh = d_in[21];
  const void* fcW = d_in[22];
  const void* fcb = d_in[23];
  float* out = (float*)d_out;  // reference output dtype is float32

  // ---- workspace layout ----
  size_t need = 0;
  auto place = [&](size_t bytes) {
    size_t off = need;
    need += (bytes + 255) & ~(size_t)255;
    return off;
  };
  size_t o_bse = place((size_t)B * S * 2 * H * 2);   // bf16 (B,S,2H)
  size_t o_proj = place((size_t)B * S * H * 2);      // bf16 (B,S,H)
  size_t o_hd = place((size_t)B * H * 4);            // f32 (B,256)
  size_t o_gi = place((size_t)B * 3 * H * 4);        // f32 (B,768)
  size_t o_gh = place((size_t)B * 3 * H * 4);        // f32 (B,768)
  size_t o_xg = place((size_t)B * (E + 2 * H) * 4);  // f32 (B,812); hfb overlay
  size_t o_cat2 = place((size_t)B * (H + 2 * H + E) * 4);  // f32 (B,1068)
  size_t o_hWh = place((size_t)B * H * 4);                 // f32 (B,256)
  size_t o_flag = place(256);                              // dtype flag

  if (ws_size < need) {
    sentinel_kernel<<<(out_size + 255) / 256, 256, 0, stream>>>(out, out_size);
    return;
  }

  char* base = (char*)d_ws;
  bf16* enc_bse = (bf16*)(base + o_bse);
  bf16* enc_proj = (bf16*)(base + o_proj);
  float* h_d = (float*)(base + o_hd);
  float* gi = (float*)(base + o_gi);
  float* gh = (float*)(base + o_gh);
  float* xg = (float*)(base + o_xg);
  float* cat2 = (float*)(base + o_cat2);
  float* hWh = (float*)(base + o_hWh);
  unsigned* dflag = (unsigned*)(base + o_flag);
  float* hfb = xg;  // (B,512) f32 overlay; encoder-only lifetime

  detect_kernel<<<1, 256, 0, stream>>>(enc_emb, dflag);

  (void)hipMemsetAsync(hfb, 0, (size_t)B * 2 * H * 4, stream);
  (void)hipMemsetAsync(out, 0, (size_t)B * VOUT * 4, stream);  // outputs[0]=0

  // ---- encoder forward (h_f = hfb[:,0:256], ldh=512) ----
  for (int s = 0; s < S; s++) {
    gemm_gather(enc_emb, E, src + (size_t)s * B, enc_Wih_f, enc_bih_f, gi, B,
                E, 3 * H, dflag, stream);
    gemm<float, false, 0>(hfb, 512, enc_Whh_f, enc_bhh_f, gh, B, H, 3 * H,
                          dflag, stream);
    gru_cell_kernel<<<B, 256, 0, stream>>>(gi, gh, hfb, 512,
                                           enc_bse + (size_t)s * 2 * H,
                                           S * 2 * H, nullptr, 0);
  }
  // ---- encoder backward (h_b = hfb[:,256:512], ldh=512) ----
  for (int s = 0; s < S; s++) {
    int pos = S - 1 - s;
    gemm_gather(enc_emb, E, src + (size_t)pos * B, enc_Wih_b, enc_bih_b, gi, B,
                E, 3 * H, dflag, stream);
    gemm<float, false, 0>(hfb + H, 512, enc_Whh_b, enc_bhh_b, gh, B, H, 3 * H,
                          dflag, stream);
    gru_cell_kernel<<<B, 256, 0, stream>>>(gi, gh, hfb + H, 512,
                                           enc_bse + (size_t)pos * 2 * H + H,
                                           S * 2 * H, nullptr, 0);
  }
  // hidden = tanh(concat(h_f,h_b) @ enc_fcW + enc_fcb) -> h_d
  gemm<float, false, 1>(hfb, 512, enc_fcW, enc_fcb, h_d, B, 2 * H, H, dflag,
                        stream);
  // enc_proj = enc_bse @ attn_We + attn_b (attn_b folded here)
  gemm<bf16, true, 0>(enc_bse, 512, attn_We, attn_b, enc_proj, B * S, 2 * H, H,
                      dflag, stream);

  // ---- decoder ----
  for (int t = 0; t < T - 1; t++) {
    embed_dec_kernel<<<(B * E) / 256, 256, 0, stream>>>(
        trg + (size_t)t * B, dec_emb, xg, cat2, dflag);
    gemm<float, false, 0>(h_d, 256, attn_Wh, nullptr, hWh, B, H, H, dflag,
                          stream);
    attn_kernel<<<B, 256, 0, stream>>>(hWh, enc_proj, enc_bse, attn_v, xg,
                                       cat2, dflag);
    gemm<float, false, 0>(xg, 812, dec_Wih, dec_bih, gi, B, E + 2 * H, 3 * H,
                          dflag, stream);
    gemm<float, false, 0>(h_d, 256, dec_Whh, dec_bhh, gh, B, H, 3 * H, dflag,
                          stream);
    gru_cell_kernel<<<B, 256, 0, stream>>>(gi, gh, h_d, 256, nullptr, 0, cat2,
                                           H + 2 * H + E);
    gemm<float, false, 0>(cat2, 1068, fcW, fcb,
                          out + (size_t)(t + 1) * B * VOUT, B, H + 2 * H + E,
                          VOUT, dflag, stream);
  }
}

// Round 6
// 4044.802 us; speedup vs baseline: 3.2894x; 3.2894x over previous
//
#include <hip/hip_runtime.h>
#include <hip/hip_bf16.h>

typedef __hip_bfloat16 bf16;
typedef __attribute__((ext_vector_type(8))) short short8;
typedef __attribute__((ext_vector_type(4))) float f32x4;

__device__ __forceinline__ float to_f(float x) { return x; }
__device__ __forceinline__ float to_f(bf16 x) { return __bfloat162float(x); }
__device__ __forceinline__ float ldp(const void* p, size_t i, bool f32) {
  return f32 ? ((const float*)p)[i] : __bfloat162float(((const bf16*)p)[i]);
}
__device__ __forceinline__ short f2b(float f) {
  bf16 h = __float2bfloat16(f);
  return *reinterpret_cast<short*>(&h);
}

// dtype probe: f32 data read as u16 pairs shows implausible bf16 exponents.
__global__ void detect_kernel(const void* __restrict__ probe,
                              unsigned* __restrict__ flag) {
  __shared__ int sbad;
  if (threadIdx.x == 0) sbad = 0;
  __syncthreads();
  const unsigned short* u = (const unsigned short*)probe;
  int bad = 0;
  for (int i = threadIdx.x; i < 2048; i += 256) {
    unsigned short w = u[i];
    unsigned e = (w >> 7) & 0xFFu;
    bool plaus = (w == 0) || (w == 0x8000u) || (e >= 0x60u && e <= 0x7Eu);
    if (!plaus) bad++;
  }
  atomicAdd(&sbad, bad);
  __syncthreads();
  if (threadIdx.x == 0) *flag = (sbad > 100) ? 1u : 0u;
}

// ---- weight prep: convert params (f32|bf16) to bf16 ws copies, with ----
// ---- row-stride remap (Wcomb build, fcW row permutation). src==null->0 ----
#define MAXSEG 24
struct PrepArgs {
  int nseg;
  const void* src[MAXSEG];
  long long soff[MAXSEG];
  short* dst[MAXSEG];
  int scols[MAXSEG];
  int dstride[MAXSEG];
  long long prefix[MAXSEG + 1];
};
__global__ void prep_kernel(PrepArgs a, const unsigned* __restrict__ dflag) {
  const bool isf32 = (*dflag != 0u);
  long long i = (long long)blockIdx.x * 256 + threadIdx.x;
  if (i >= a.prefix[a.nseg]) return;
  int s = 0;
  while (i >= a.prefix[s + 1]) s++;
  long long loc = i - a.prefix[s];
  int r = (int)(loc / a.scols[s]), c = (int)(loc % a.scols[s]);
  float v = a.src[s] ? ldp(a.src[s], (size_t)(a.soff[s] + loc), isf32) : 0.f;
  a.dst[s][(long long)r * a.dstride[s] + c] = f2b(v);
}

// ---- MFMA GEMM: C(M,N) = act(A(M,K) @ W(K,N) + bias) ----
// A: f32 (TA=float) or bf16 (TA=bf16) ws tensor with row stride lda, or
// GATHER: rows emb[rowidx[m]] (dual-dtype param). W,bias: prepped bf16.
// M%64==0, N%64==0; K tail guarded. 256 thr = 4 waves; block tile 64x64;
// wave w owns rows w*16..w*16+15 across 4 col-groups of 16; K-step 32.
// Frag layouts (HW-verified m89/m91): A/B [dim=lane&15][k=(lane>>4)*8+j],
// C/D col=lane&15, row=(lane>>4)*4+r.
template <typename TA, bool GATHER, bool OUT_BF16, int ACT>
__global__ __launch_bounds__(256) void mgemm_kernel(
    const void* __restrict__ Av, int lda, const int* __restrict__ rowidx,
    const bf16* __restrict__ W, const bf16* __restrict__ bias,
    void* __restrict__ Cv, int M, int K, int N,
    const unsigned* __restrict__ dflag) {
  __shared__ short Asm[64][40];  // [m][k], stride 40 (80B): b128-aligned,
  __shared__ short Bsm[64][40];  // 2-way-max bank aliasing on frag reads
  __shared__ int rows[64];
  const int tid = threadIdx.x;
  const int lane = tid & 63, wave = tid >> 6;
  const int m0 = blockIdx.y * 64, n0 = blockIdx.x * 64;
  bool isf32 = true;
  if (GATHER) {
    isf32 = (*dflag != 0u);
    if (tid < 64) rows[tid] = rowidx[m0 + tid];
    __syncthreads();
  }
  f32x4 acc[4];
#pragma unroll
  for (int g = 0; g < 4; g++) acc[g] = 0.f;

  const int am = tid >> 2, aks = (tid & 3) * 8;  // A staging: 8 k-contig
  const int bk = tid >> 3, bns = (tid & 7) * 8;  // B staging: 8 n-contig
  const long long arow = GATHER ? (long long)rows[am] : (long long)(m0 + am);

  for (int k0 = 0; k0 < K; k0 += 32) {
    // ---- stage A tile (64x32) ----
    short8 av;
    if (k0 + 32 <= K) {
      if (sizeof(TA) == 2 && !GATHER) {
        av = *(const short8*)((const short*)Av + arow * lda + k0 + aks);
      } else if (!GATHER || isf32) {
        const float* Af = (const float*)Av;
        const float4* p = (const float4*)(Af + arow * lda + k0 + aks);
        float4 f0 = p[0], f1 = p[1];
        av[0] = f2b(f0.x); av[1] = f2b(f0.y);
        av[2] = f2b(f0.z); av[3] = f2b(f0.w);
        av[4] = f2b(f1.x); av[5] = f2b(f1.y);
        av[6] = f2b(f1.z); av[7] = f2b(f1.w);
      } else {
        av = *(const short8*)((const short*)Av + arow * lda + k0 + aks);
      }
    } else {
#pragma unroll
      for (int j = 0; j < 8; j++) {
        int k = k0 + aks + j;
        float f = 0.f;
        if (k < K) {
          if (GATHER) f = ldp(Av, (size_t)(arow * lda + k), isf32);
          else f = to_f(((const TA*)Av)[arow * lda + k]);
        }
        av[j] = f2b(f);
      }
    }
    *(short8*)&Asm[am][aks] = av;
    // ---- stage B tile (32k x 64n), transposed into [n][k] ----
    short8 wv;
    if (k0 + bk < K) {
      wv = *(const short8*)((const short*)W + (long long)(k0 + bk) * N + n0 +
                            bns);
    } else {
#pragma unroll
      for (int j = 0; j < 8; j++) wv[j] = 0;
    }
#pragma unroll
    for (int j = 0; j < 8; j++) Bsm[bns + j][bk] = wv[j];
    __syncthreads();
    // ---- MFMA ----
    short8 a = *(short8*)&Asm[wave * 16 + (lane & 15)][(lane >> 4) * 8];
#pragma unroll
    for (int g = 0; g < 4; g++) {
      short8 b = *(short8*)&Bsm[g * 16 + (lane & 15)][(lane >> 4) * 8];
      acc[g] = __builtin_amdgcn_mfma_f32_16x16x32_bf16(a, b, acc[g], 0, 0, 0);
    }
    __syncthreads();
  }
  // ---- epilogue ----
#pragma unroll
  for (int g = 0; g < 4; g++) {
    int col = n0 + g * 16 + (lane & 15);
    float bv = bias ? __bfloat162float(bias[col]) : 0.f;
#pragma unroll
    for (int r = 0; r < 4; r++) {
      int row = m0 + wave * 16 + (lane >> 4) * 4 + r;
      float v = acc[g][r] + bv;
      if (ACT == 1) v = tanhf(v);
      if (OUT_BF16)
        ((bf16*)Cv)[(long long)row * N + col] = __float2bfloat16(v);
      else
        ((float*)Cv)[(long long)row * N + col] = v;
    }
  }
}

template <typename TA, bool GATHER, bool OB, int ACT>
static void mgemm(const void* A, int lda, const int* rows, const bf16* W,
                  const bf16* bias, void* C, int M, int K, int N,
                  const unsigned* dflag, hipStream_t s) {
  dim3 g(N / 64, M / 64);
  mgemm_kernel<TA, GATHER, OB, ACT>
      <<<g, 256, 0, s>>>(A, lda, rows, W, bias, C, M, K, N, dflag);
}

// GRU cell: h (stride ldh) in place; gi dtype templated (bf16 batched path).
template <typename TGI>
__global__ __launch_bounds__(256) void gru_cell_kernel(
    const TGI* __restrict__ gi, int ldgi, const float* __restrict__ gh,
    int ldgh, float* __restrict__ h, int ldh, bf16* __restrict__ aux_bf16,
    int stride_b, float* __restrict__ aux_f32, int stride_f) {
  int b = blockIdx.x, i = threadIdx.x;
  const TGI* gib = gi + (long long)b * ldgi;
  const float* ghb = gh + (long long)b * ldgh;
  float ir = to_f(gib[i]), iz = to_f(gib[256 + i]), in_ = to_f(gib[512 + i]);
  float hr = ghb[i], hz = ghb[256 + i], hn = ghb[512 + i];
  float hv = h[(long long)b * ldh + i];
  float r = 1.f / (1.f + expf(-(ir + hr)));
  float z = 1.f / (1.f + expf(-(iz + hz)));
  float n = tanhf(in_ + r * hn);
  float out = (1.f - z) * n + z * hv;
  h[(long long)b * ldh + i] = out;
  if (aux_bf16) aux_bf16[(long long)b * stride_b + i] = __float2bfloat16(out);
  if (aux_f32) aux_f32[(long long)b * stride_f + i] = out;
}

// attention + decoder-embedding fused. Per block b:
//   score[s]=sum_i v[i]*tanh(hWh[b,i]+proj[b,s,i]); softmax; weighted.
//   hWh read from ghw[b*1024+768+i]. Writes xgc[b][0:300]=emb(trg),
//   xgc[b][300:812]=weighted. (xgc stride 1068; cols 812:1068 = hn by cell.)
__global__ __launch_bounds__(256) void attn_kernel(
    const float* __restrict__ ghw, const bf16* __restrict__ proj,
    const bf16* __restrict__ bse, const void* __restrict__ v,
    const int* __restrict__ trg_t, const void* __restrict__ emb,
    float* __restrict__ xgc, const unsigned* __restrict__ dflag) {
  const bool isf32 = (*dflag != 0u);
  int b = blockIdx.x, tid = threadIdx.x;
  int wave = tid >> 6, lane = tid & 63;
  __shared__ float partial[24][4];
  __shared__ float aw[24];
  float vh = ghw[(long long)b * 1024 + 768 + tid];
  float vv = ldp(v, tid, isf32);
  const bf16* pb = proj + (long long)b * 24 * 256;
#pragma unroll 4
  for (int s = 0; s < 24; s++) {
    float e = tanhf(vh + __bfloat162float(pb[s * 256 + tid]));
    float t = vv * e;
#pragma unroll
    for (int off = 32; off > 0; off >>= 1) t += __shfl_down(t, off, 64);
    if (lane == 0) partial[s][wave] = t;
  }
  __syncthreads();
  if (tid == 0) {
    float sc[24];
    float mx = -1e30f;
    for (int s = 0; s < 24; s++) {
      float xv = partial[s][0] + partial[s][1] + partial[s][2] + partial[s][3];
      sc[s] = xv;
      mx = fmaxf(mx, xv);
    }
    float sum = 0.f;
    for (int s = 0; s < 24; s++) {
      sc[s] = expf(sc[s] - mx);
      sum += sc[s];
    }
    float inv = 1.f / sum;
    for (int s = 0; s < 24; s++) aw[s] = sc[s] * inv;
  }
  __syncthreads();
  const bf16* eb = bse + (long long)b * 24 * 512;
  float w0 = 0.f, w1 = 0.f;
#pragma unroll 4
  for (int s = 0; s < 24; s++) {
    float a = aw[s];
    w0 += a * __bfloat162float(eb[s * 512 + tid]);
    w1 += a * __bfloat162float(eb[s * 512 + 256 + tid]);
  }
  float* xb = xgc + (long long)b * 1068;
  xb[300 + tid] = w0;
  xb[300 + 256 + tid] = w1;
  long long row = trg_t[b];
  for (int e = tid; e < 300; e += 256) xb[e] = ldp(emb, row * 300 + e, isf32);
}

__global__ void sentinel_kernel(float* out, int n) {
  int i = blockIdx.x * 256 + threadIdx.x;
  if (i < n) out[i] = 123.0f;
}

extern "C" void kernel_launch(void* const* d_in, const int* in_sizes, int n_in,
                              void* d_out, int out_size, void* d_ws,
                              size_t ws_size, hipStream_t stream) {
  const int B = 2048, S = 24, T = 25, H = 256, E = 300, VOUT = 128;
  const int* src = (const int*)d_in[0];
  const int* trg = (const int*)d_in[1];
  const void* enc_emb = d_in[2];
  const void* enc_Wih_f = d_in[3];
  const void* enc_Whh_f = d_in[4];
  const void* enc_bih_f = d_in[5];
  const void* enc_bhh_f = d_in[6];
  const void* enc_Wih_b = d_in[7];
  const void* enc_Whh_b = d_in[8];
  const void* enc_bih_b = d_in[9];
  const void* enc_bhh_b = d_in[10];
  const void* enc_fcW = d_in[11];
  const void* enc_fcb = d_in[12];
  const void* attn_Wh = d_in[13];
  const void* attn_We = d_in[14];
  const void* attn_b = d_in[15];
  const void* attn_v = d_in[16];
  const void* dec_emb = d_in[17];
  const void* dec_Wih = d_in[18];
  const void* dec_Whh = d_in[19];
  const void* dec_bih = d_in[20];
  const void* dec_bhh = d_in[21];
  const void* fcW = d_in[22];
  const void* fcb = d_in[23];
  float* out = (float*)d_out;

  // ---- common workspace layout ----
  size_t need = 0;
  auto place = [&](size_t bytes) {
    size_t off = need;
    need += (bytes + 255) & ~(size_t)255;
    return off;
  };
  size_t o_flag = place(256);
  // prepped bf16 weights/biases
  size_t oW1 = place(230400 * 2);   // enc_Wih_f 300x768
  size_t oW2 = place(196608 * 2);   // enc_Whh_f 256x768
  size_t oW3 = place(230400 * 2);   // enc_Wih_b
  size_t oW4 = place(196608 * 2);   // enc_Whh_b
  size_t oW5 = place(131072 * 2);   // enc_fcW 512x256
  size_t oW6 = place(131072 * 2);   // attn_We 512x256
  size_t oWc = place(262144 * 2);   // [dec_Whh | attn_Wh] 256x1024
  size_t oW7 = place(623616 * 2);   // dec_Wih 812x768
  size_t oW8 = place(136704 * 2);   // fcW row-permuted 1068x128
  size_t oB1 = place(768 * 2);      // enc_bih_f
  size_t oB2 = place(768 * 2);      // enc_bhh_f
  size_t oB3 = place(768 * 2);      // enc_bih_b
  size_t oB4 = place(768 * 2);      // enc_bhh_b
  size_t oB5 = place(256 * 2);      // enc_fcb
  size_t oB6 = place(256 * 2);      // attn_b
  size_t oB7 = place(768 * 2);      // dec_bih
  size_t oBc = place(1024 * 2);     // [dec_bhh | zeros]
  size_t oB8 = place(128 * 2);      // fcb
  size_t o_bse = place((size_t)B * S * 512 * 2);  // bf16 (B,S,2H)
  size_t o_hd = place((size_t)B * 256 * 4);
  size_t o_U = place((size_t)B * 1024 * 4);  // enc gh (x768) / dec ghw (x1024)
  size_t need_common = need;
  // non-batched extras
  size_t o_proj_nb = place((size_t)B * S * 256 * 2);
  size_t o_xgc_nb = place((size_t)B * 1068 * 4);
  size_t o_gib_nb = place((size_t)B * 768 * 4);
  size_t need_nb = need;
  // batched layout: R region + separate hfb
  size_t need2 = need_common;
  auto place2 = [&](size_t bytes) {
    size_t off = need2;
    need2 += (bytes + 255) & ~(size_t)255;
    return off;
  };
  size_t o_R = place2((size_t)S * B * 768 * 2);  // gi_all bf16 (75.5 MB)
  size_t o_hfb_b = place2((size_t)B * 512 * 4);
  size_t need_b = need2;

  const bool batched = (ws_size >= need_b);
  if (!batched && ws_size < need_nb) {
    sentinel_kernel<<<(out_size + 255) / 256, 256, 0, stream>>>(out, out_size);
    return;
  }

  char* base = (char*)d_ws;
  unsigned* dflag = (unsigned*)(base + o_flag);
  bf16* W1 = (bf16*)(base + oW1);
  bf16* W2 = (bf16*)(base + oW2);
  bf16* W3 = (bf16*)(base + oW3);
  bf16* W4 = (bf16*)(base + oW4);
  bf16* W5 = (bf16*)(base + oW5);
  bf16* W6 = (bf16*)(base + oW6);
  bf16* Wc = (bf16*)(base + oWc);
  bf16* W7 = (bf16*)(base + oW7);
  bf16* W8 = (bf16*)(base + oW8);
  bf16 *B1 = (bf16*)(base + oB1), *B2 = (bf16*)(base + oB2);
  bf16 *B3 = (bf16*)(base + oB3), *B4 = (bf16*)(base + oB4);
  bf16 *B5 = (bf16*)(base + oB5), *B6 = (bf16*)(base + oB6);
  bf16 *B7 = (bf16*)(base + oB7), *Bc = (bf16*)(base + oBc);
  bf16* B8 = (bf16*)(base + oB8);
  bf16* enc_bse = (bf16*)(base + o_bse);
  float* h_d = (float*)(base + o_hd);
  float* ghU = (float*)(base + o_U);  // enc: gh stride 768; dec: ghw 1024

  bf16* gi_all = nullptr;
  bf16* proj;
  float *xgc, *gibuf, *hfb;
  if (batched) {
    gi_all = (bf16*)(base + o_R);
    char* r = base + o_R;  // decoder-phase reuse of the gi_all region
    size_t rn = 0;
    auto rp = [&](size_t bytes) {
      size_t off = rn;
      rn += (bytes + 255) & ~(size_t)255;
      return off;
    };
    proj = (bf16*)(r + rp((size_t)B * S * 256 * 2));
    xgc = (float*)(r + rp((size_t)B * 1068 * 4));
    gibuf = (float*)(r + rp((size_t)B * 768 * 4));
    hfb = (float*)(base + o_hfb_b);
  } else {
    proj = (bf16*)(base + o_proj_nb);
    xgc = (float*)(base + o_xgc_nb);
    gibuf = (float*)(base + o_gib_nb);
    hfb = xgc;  // overlay: hfb is encoder-phase, xgc decoder-phase
  }

  detect_kernel<<<1, 256, 0, stream>>>(enc_emb, dflag);

  // ---- weight prep ----
  PrepArgs pa;
  int ns = 0;
  long long tot = 0;
  auto seg = [&](const void* s, long long soff, bf16* dst, int scols,
                 int dstride, long long count) {
    pa.src[ns] = s;
    pa.soff[ns] = soff;
    pa.dst[ns] = (short*)dst;
    pa.scols[ns] = scols;
    pa.dstride[ns] = dstride;
    pa.prefix[ns] = tot;
    tot += count;
    ns++;
  };
  seg(enc_Wih_f, 0, W1, 768, 768, 230400);
  seg(enc_Whh_f, 0, W2, 768, 768, 196608);
  seg(enc_Wih_b, 0, W3, 768, 768, 230400);
  seg(enc_Whh_b, 0, W4, 768, 768, 196608);
  seg(enc_fcW, 0, W5, 256, 256, 131072);
  seg(attn_We, 0, W6, 256, 256, 131072);
  seg(dec_Whh, 0, Wc, 768, 1024, 196608);
  seg(attn_Wh, 0, Wc + 768, 256, 1024, 65536);
  seg(dec_Wih, 0, W7, 768, 768, 623616);
  // fcW row-permutation to match xgc = [emb(300) | weighted(512) | hn(256)]
  seg(fcW, 768 * 128, W8, 128, 128, 300 * 128);        // emb rows
  seg(fcW, 256 * 128, W8 + 300 * 128, 128, 128, 512 * 128);  // weighted rows
  seg(fcW, 0, W8 + 812 * 128, 128, 128, 256 * 128);    // hn rows
  seg(enc_bih_f, 0, B1, 768, 768, 768);
  seg(enc_bhh_f, 0, B2, 768, 768, 768);
  seg(enc_bih_b, 0, B3, 768, 768, 768);
  seg(enc_bhh_b, 0, B4, 768, 768, 768);
  seg(enc_fcb, 0, B5, 256, 256, 256);
  seg(attn_b, 0, B6, 256, 256, 256);
  seg(dec_bih, 0, B7, 768, 768, 768);
  seg(dec_bhh, 0, Bc, 768, 768, 768);
  seg(nullptr, 0, Bc + 768, 256, 256, 256);  // zero bias for hWh part
  seg(fcb, 0, B8, 128, 128, 128);
  pa.prefix[ns] = tot;
  pa.nseg = ns;
  prep_kernel<<<(int)((tot + 255) / 256), 256, 0, stream>>>(pa, dflag);

  (void)hipMemsetAsync(hfb, 0, (size_t)B * 512 * 4, stream);
  (void)hipMemsetAsync(out, 0, (size_t)B * VOUT * 4, stream);  // outputs[0]=0

  // ---- encoder ----
  if (batched) {
    mgemm<float, true, true, 0>(enc_emb, E, src, W1, B1, gi_all, S * B, E,
                                768, dflag, stream);
    for (int s = 0; s < S; s++) {
      mgemm<float, false, false, 0>(hfb, 512, nullptr, W2, B2, ghU, B, H, 768,
                                    dflag, stream);
      gru_cell_kernel<bf16><<<B, 256, 0, stream>>>(
          gi_all + (size_t)s * B * 768, 768, ghU, 768, hfb, 512,
          enc_bse + (size_t)s * 512, S * 512, nullptr, 0);
    }
    mgemm<float, true, true, 0>(enc_emb, E, src, W3, B3, gi_all, S * B, E,
                                768, dflag, stream);
    for (int s = 0; s < S; s++) {
      int pos = S - 1 - s;
      mgemm<float, false, false, 0>(hfb + H, 512, nullptr, W4, B4, ghU, B, H,
                                    768, dflag, stream);
      gru_cell_kernel<bf16><<<B, 256, 0, stream>>>(
          gi_all + (size_t)pos * B * 768, 768, ghU, 768, hfb + H, 512,
          enc_bse + (size_t)pos * 512 + 256, S * 512, nullptr, 0);
    }
  } else {
    for (int s = 0; s < S; s++) {
      mgemm<float, true, false, 0>(enc_emb, E, src + (size_t)s * B, W1, B1,
                                   gibuf, B, E, 768, dflag, stream);
      mgemm<float, false, false, 0>(hfb, 512, nullptr, W2, B2, ghU, B, H, 768,
                                    dflag, stream);
      gru_cell_kernel<float><<<B, 256, 0, stream>>>(
          gibuf, 768, ghU, 768, hfb, 512, enc_bse + (size_t)s * 512, S * 512,
          nullptr, 0);
    }
    for (int s = 0; s < S; s++) {
      int pos = S - 1 - s;
      mgemm<float, true, false, 0>(enc_emb, E, src + (size_t)pos * B, W3, B3,
                                   gibuf, B, E, 768, dflag, stream);
      mgemm<float, false, false, 0>(hfb + H, 512, nullptr, W4, B4, ghU, B, H,
                                    768, dflag, stream);
      gru_cell_kernel<float><<<B, 256, 0, stream>>>(
          gibuf, 768, ghU, 768, hfb + H, 512,
          enc_bse + (size_t)pos * 512 + 256, S * 512, nullptr, 0);
    }
  }
  // hidden = tanh([h_f,h_b] @ enc_fcW + enc_fcb)
  mgemm<float, false, false, 1>(hfb, 512, nullptr, W5, B5, h_d, B, 512, 256,
                                dflag, stream);
  // enc_proj = enc_bse @ attn_We + attn_b
  mgemm<bf16, false, true, 0>(enc_bse, 512, nullptr, W6, B6, proj, B * S, 512,
                              256, dflag, stream);

  // ---- decoder ----
  for (int t = 0; t < T - 1; t++) {
    // [gh | hWh] = h_d @ [dec_Whh | attn_Wh] + [dec_bhh | 0]
    mgemm<float, false, false, 0>(h_d, 256, nullptr, Wc, Bc, ghU, B, H, 1024,
                                  dflag, stream);
    attn_kernel<<<B, 256, 0, stream>>>(ghU, proj, enc_bse, attn_v,
                                       trg + (size_t)t * B, dec_emb, xgc,
                                       dflag);
    mgemm<float, false, false, 0>(xgc, 1068, nullptr, W7, B7, gibuf, B, 812,
                                  768, dflag, stream);
    gru_cell_kernel<float><<<B, 256, 0, stream>>>(gibuf, 768, ghU, 1024, h_d,
                                                  256, nullptr, 0, xgc + 812,
                                                  1068);
    mgemm<float, false, false, 0>(xgc, 1068, nullptr, W8, B8,
                                  out + (size_t)(t + 1) * B * VOUT, B, 1068,
                                  VOUT, dflag, stream);
  }
}

// Round 7
// 2924.767 us; speedup vs baseline: 4.5491x; 1.3829x over previous
//
#include <hip/hip_runtime.h>
#include <hip/hip_bf16.h>

typedef __hip_bfloat16 bf16;
typedef __attribute__((ext_vector_type(8))) short short8;
typedef __attribute__((ext_vector_type(4))) float f32x4;

__device__ __forceinline__ float to_f(float x) { return x; }
__device__ __forceinline__ float to_f(bf16 x) { return __bfloat162float(x); }
__device__ __forceinline__ float ldp(const void* p, size_t i, bool f32) {
  return f32 ? ((const float*)p)[i] : __bfloat162float(((const bf16*)p)[i]);
}
__device__ __forceinline__ short f2b(float f) {
  bf16 h = __float2bfloat16(f);
  return *reinterpret_cast<short*>(&h);
}

// dtype probe (kept for robustness): f32 data read as u16 pairs shows
// implausible bf16 exponents ~88% of the time.
__global__ void detect_kernel(const void* __restrict__ probe,
                              unsigned* __restrict__ flag) {
  __shared__ int sbad;
  if (threadIdx.x == 0) sbad = 0;
  __syncthreads();
  const unsigned short* u = (const unsigned short*)probe;
  int bad = 0;
  for (int i = threadIdx.x; i < 2048; i += 256) {
    unsigned short w = u[i];
    unsigned e = (w >> 7) & 0xFFu;
    bool plaus = (w == 0) || (w == 0x8000u) || (e >= 0x60u && e <= 0x7Eu);
    if (!plaus) bad++;
  }
  atomicAdd(&sbad, bad);
  __syncthreads();
  if (threadIdx.x == 0) *flag = (sbad > 100) ? 1u : 0u;
}

// ---- weight prep: params (f32|bf16) -> bf16 ws copies; optional transpose
// (dst[c*dstride+r]) so GEMM B-tiles load W^T rows coalesced. src null -> 0.
#define MAXSEG 24
struct PrepArgs {
  int nseg;
  const void* src[MAXSEG];
  long long soff[MAXSEG];
  short* dst[MAXSEG];
  int scols[MAXSEG];
  int dstride[MAXSEG];
  int transp[MAXSEG];
  long long prefix[MAXSEG + 1];
};
__global__ void prep_kernel(PrepArgs a, const unsigned* __restrict__ dflag) {
  const bool isf32 = (*dflag != 0u);
  long long i = (long long)blockIdx.x * 256 + threadIdx.x;
  if (i >= a.prefix[a.nseg]) return;
  int s = 0;
  while (i >= a.prefix[s + 1]) s++;
  long long loc = i - a.prefix[s];
  long long r = loc / a.scols[s], c = loc % a.scols[s];
  float v = a.src[s] ? ldp(a.src[s], (size_t)(a.soff[s] + loc), isf32) : 0.f;
  long long idx = a.transp[s] ? (c * a.dstride[s] + r) : (r * a.dstride[s] + c);
  a.dst[s][idx] = f2b(v);
}

// ---- multi-job MFMA GEMM ----
// Per blockIdx.z job: C(M,N) = act(A(M,K) @ WT^T + bias). A is bf16 ws tensor
// (lda) or gathered param emb rows (dual-dtype). WT is prepped bf16 W^T
// [n][k] (stride wst) -> B staging is coalesced + conflict-free. Outputs:
// Cf (f32) and/or Ch (bf16), row stride N. flags: 1=gather, 4=tanh.
struct GJob {
  const void* A;
  const int* rowidx;
  const short* WT;
  const bf16* bias;
  float* Cf;
  bf16* Ch;
  int lda, wst, K, M, N, flags;
};
struct GJobs {
  GJob j[4];
};

__global__ __launch_bounds__(256) void mj_gemm(
    GJobs args, const unsigned* __restrict__ dflag) {
  GJob jb = args.j[blockIdx.z];
  const int n0 = blockIdx.x * 64, m0 = blockIdx.y * 64;
  if (n0 >= jb.N || m0 >= jb.M) return;
  __shared__ short Asm[64][40];  // [m][k] pad->40: frag reads 2-way max (free)
  __shared__ short Bsm[64][40];  // [n][k]
  __shared__ int rows[64];
  const int tid = threadIdx.x, lane = tid & 63, wave = tid >> 6;
  const bool gather = (jb.flags & 1) != 0;
  const bool isf32 = gather && (*dflag != 0u);
  if (gather) {
    if (tid < 64) rows[tid] = jb.rowidx[m0 + tid];
    __syncthreads();
  }
  f32x4 acc[4];
#pragma unroll
  for (int g = 0; g < 4; g++) acc[g] = 0.f;

  const int ar = tid >> 2, aks = (tid & 3) * 8;  // row 0..63, k-off 0/8/16/24
  const long long arow = gather ? (long long)rows[ar] : (long long)(m0 + ar);
  const int K = jb.K;
  const short* wrow = jb.WT + (long long)(n0 + ar) * jb.wst;

  for (int k0 = 0; k0 < K; k0 += 32) {
    short8 av;
    if (k0 + 32 <= K) {
      if (gather && isf32) {
        const float4* p =
            (const float4*)((const float*)jb.A + arow * jb.lda + k0 + aks);
        float4 f0 = p[0], f1 = p[1];
        av[0] = f2b(f0.x); av[1] = f2b(f0.y);
        av[2] = f2b(f0.z); av[3] = f2b(f0.w);
        av[4] = f2b(f1.x); av[5] = f2b(f1.y);
        av[6] = f2b(f1.z); av[7] = f2b(f1.w);
      } else {
        av = *(const short8*)((const short*)jb.A + arow * jb.lda + k0 + aks);
      }
    } else {
#pragma unroll
      for (int j = 0; j < 8; j++) {
        int k = k0 + aks + j;
        float f = 0.f;
        if (k < K)
          f = gather ? ldp(jb.A, (size_t)(arow * jb.lda + k), isf32)
                     : to_f(((const bf16*)jb.A)[arow * jb.lda + k]);
        av[j] = f2b(f);
      }
    }
    *(short8*)&Asm[ar][aks] = av;

    short8 wv;
    if (k0 + 32 <= K) {
      wv = *(const short8*)(wrow + k0 + aks);
    } else {
#pragma unroll
      for (int j = 0; j < 8; j++) {
        int k = k0 + aks + j;
        wv[j] = (k < K) ? wrow[k] : (short)0;
      }
    }
    *(short8*)&Bsm[ar][aks] = wv;
    __syncthreads();

    short8 a = *(short8*)&Asm[wave * 16 + (lane & 15)][(lane >> 4) * 8];
#pragma unroll
    for (int g = 0; g < 4; g++) {
      short8 b = *(short8*)&Bsm[g * 16 + (lane & 15)][(lane >> 4) * 8];
      acc[g] = __builtin_amdgcn_mfma_f32_16x16x32_bf16(a, b, acc[g], 0, 0, 0);
    }
    __syncthreads();
  }

  const int N = jb.N;
#pragma unroll
  for (int g = 0; g < 4; g++) {
    int col = n0 + g * 16 + (lane & 15);
    float bv = jb.bias ? to_f(jb.bias[col]) : 0.f;
#pragma unroll
    for (int r = 0; r < 4; r++) {
      int row = m0 + wave * 16 + (lane >> 4) * 4 + r;
      float v = acc[g][r] + bv;
      if (jb.flags & 4) v = tanhf(v);
      if (jb.Cf) jb.Cf[(long long)row * N + col] = v;
      if (jb.Ch) jb.Ch[(long long)row * N + col] = __float2bfloat16(v);
    }
  }
}

// encoder dual-direction GRU cell. U = 4 segs of (B,768) bf16:
// [gi_f, gh_f, gi_b, gh_b]. dir = blockIdx.y. Writes hfb f32, hbf bf16
// mirror, and enc_bse slot (fwd at s, bwd at 23-s).
__global__ __launch_bounds__(256) void enc_cell(
    const bf16* __restrict__ U, float* __restrict__ hfb,
    bf16* __restrict__ hbf, bf16* __restrict__ bse, int s) {
  int dir = blockIdx.y, b = blockIdx.x, i = threadIdx.x;
  const bf16* gi = U + ((long long)(dir * 2) * 2048 + b) * 768;
  const bf16* gh = U + ((long long)(dir * 2 + 1) * 2048 + b) * 768;
  float ir = to_f(gi[i]), iz = to_f(gi[256 + i]), in_ = to_f(gi[512 + i]);
  float hr = to_f(gh[i]), hz = to_f(gh[256 + i]), hn = to_f(gh[512 + i]);
  long long hidx = (long long)b * 512 + dir * 256 + i;
  float hv = hfb[hidx];
  float r = 1.f / (1.f + expf(-(ir + hr)));
  float z = 1.f / (1.f + expf(-(iz + hz)));
  float n = tanhf(in_ + r * hn);
  float o = (1.f - z) * n + z * hv;
  hfb[hidx] = o;
  hbf[hidx] = __float2bfloat16(o);
  int pos = dir ? (23 - s) : s;
  bse[(long long)b * (24 * 512) + pos * 512 + dir * 256 + i] =
      __float2bfloat16(o);
}

// decoder GRU cell: gi bf16 (B,768), gh = ghw bf16 (B,1024; first 768 cols).
// Writes h_d f32, hdbf bf16 mirror, xgc[:,812:1068] bf16 (fc input).
__global__ __launch_bounds__(256) void dec_cell(
    const bf16* __restrict__ gi, const bf16* __restrict__ ghw,
    float* __restrict__ h_d, bf16* __restrict__ hdbf, bf16* __restrict__ xgc) {
  int b = blockIdx.x, i = threadIdx.x;
  const bf16* gib = gi + (long long)b * 768;
  const bf16* ghb = ghw + (long long)b * 1024;
  float ir = to_f(gib[i]), iz = to_f(gib[256 + i]), in_ = to_f(gib[512 + i]);
  float hr = to_f(ghb[i]), hz = to_f(ghb[256 + i]), hn = to_f(ghb[512 + i]);
  float hv = h_d[(long long)b * 256 + i];
  float r = 1.f / (1.f + expf(-(ir + hr)));
  float z = 1.f / (1.f + expf(-(iz + hz)));
  float n = tanhf(in_ + r * hn);
  float o = (1.f - z) * n + z * hv;
  h_d[(long long)b * 256 + i] = o;
  hdbf[(long long)b * 256 + i] = __float2bfloat16(o);
  xgc[(long long)b * 1072 + 812 + i] = __float2bfloat16(o);
}

// attention + decoder embedding. hWh = ghw[:,768:1024] (bf16). Writes
// xgc[:,0:300]=emb(trg), xgc[:,300:812]=weighted (bf16, stride 1072).
__global__ __launch_bounds__(256) void attn_kernel(
    const bf16* __restrict__ ghw, const bf16* __restrict__ proj,
    const bf16* __restrict__ bse, const void* __restrict__ v,
    const int* __restrict__ trg_t, const void* __restrict__ emb,
    bf16* __restrict__ xgc, const unsigned* __restrict__ dflag) {
  const bool isf32 = (*dflag != 0u);
  int b = blockIdx.x, tid = threadIdx.x;
  int wave = tid >> 6, lane = tid & 63;
  __shared__ float partial[24][4];
  __shared__ float aw[24];
  float vh = to_f(ghw[(long long)b * 1024 + 768 + tid]);
  float vv = ldp(v, tid, isf32);
  const bf16* pb = proj + (long long)b * 24 * 256;
#pragma unroll 4
  for (int s = 0; s < 24; s++) {
    float e = tanhf(vh + __bfloat162float(pb[s * 256 + tid]));
    float t = vv * e;
#pragma unroll
    for (int off = 32; off > 0; off >>= 1) t += __shfl_down(t, off, 64);
    if (lane == 0) partial[s][wave] = t;
  }
  __syncthreads();
  if (tid == 0) {
    float sc[24];
    float mx = -1e30f;
    for (int s = 0; s < 24; s++) {
      float xv = partial[s][0] + partial[s][1] + partial[s][2] + partial[s][3];
      sc[s] = xv;
      mx = fmaxf(mx, xv);
    }
    float sum = 0.f;
    for (int s = 0; s < 24; s++) {
      sc[s] = expf(sc[s] - mx);
      sum += sc[s];
    }
    float inv = 1.f / sum;
    for (int s = 0; s < 24; s++) aw[s] = sc[s] * inv;
  }
  __syncthreads();
  const bf16* eb = bse + (long long)b * 24 * 512;
  float w0 = 0.f, w1 = 0.f;
#pragma unroll 4
  for (int s = 0; s < 24; s++) {
    float a = aw[s];
    w0 += a * __bfloat162float(eb[s * 512 + tid]);
    w1 += a * __bfloat162float(eb[s * 512 + 256 + tid]);
  }
  bf16* xb = xgc + (long long)b * 1072;
  xb[300 + tid] = __float2bfloat16(w0);
  xb[556 + tid] = __float2bfloat16(w1);
  long long row = trg_t[b];
  for (int e = tid; e < 300; e += 256)
    xb[e] = __float2bfloat16(ldp(emb, row * 300 + e, isf32));
}

__global__ void sentinel_kernel(float* out, int n) {
  int i = blockIdx.x * 256 + threadIdx.x;
  if (i < n) out[i] = 123.0f;
}

extern "C" void kernel_launch(void* const* d_in, const int* in_sizes, int n_in,
                              void* d_out, int out_size, void* d_ws,
                              size_t ws_size, hipStream_t stream) {
  const int B = 2048, S = 24, T = 25, E = 300, VOUT = 128;
  const int* src = (const int*)d_in[0];
  const int* trg = (const int*)d_in[1];
  const void* enc_emb = d_in[2];
  const void* enc_Wih_f = d_in[3];
  const void* enc_Whh_f = d_in[4];
  const void* enc_bih_f = d_in[5];
  const void* enc_bhh_f = d_in[6];
  const void* enc_Wih_b = d_in[7];
  const void* enc_Whh_b = d_in[8];
  const void* enc_bih_b = d_in[9];
  const void* enc_bhh_b = d_in[10];
  const void* enc_fcW = d_in[11];
  const void* enc_fcb = d_in[12];
  const void* attn_Wh = d_in[13];
  const void* attn_We = d_in[14];
  const void* attn_b = d_in[15];
  const void* attn_v = d_in[16];
  const void* dec_emb = d_in[17];
  const void* dec_Wih = d_in[18];
  const void* dec_Whh = d_in[19];
  const void* dec_bih = d_in[20];
  const void* dec_bhh = d_in[21];
  const void* fcW = d_in[22];
  const void* fcb = d_in[23];
  float* out = (float*)d_out;

  // ---- workspace layout (~102 MB; verified ws >= 107.7 MB) ----
  size_t need = 0;
  auto place = [&](size_t bytes) {
    size_t off = need;
    need += (bytes + 255) & ~(size_t)255;
    return off;
  };
  size_t o_flag = place(256);
  size_t oWT1 = place(768 * 304 * 2);   // enc_Wih_f^T
  size_t oWT2 = place(768 * 256 * 2);   // enc_Whh_f^T
  size_t oWT3 = place(768 * 304 * 2);   // enc_Wih_b^T
  size_t oWT4 = place(768 * 256 * 2);   // enc_Whh_b^T
  size_t oWT5 = place(256 * 512 * 2);   // enc_fcW^T
  size_t oWT6 = place(256 * 512 * 2);   // attn_We^T
  size_t oWcT = place(1024 * 256 * 2);  // [dec_Whh | attn_Wh]^T
  size_t oW7T = place(768 * 816 * 2);   // dec_Wih^T (stride 816)
  size_t oW8T = place(128 * 1072 * 2);  // fcW^T col-permuted (stride 1072)
  size_t oB1 = place(768 * 2), oB2 = place(768 * 2);
  size_t oB3 = place(768 * 2), oB4 = place(768 * 2);
  size_t oB5 = place(256 * 2), oB6 = place(256 * 2);
  size_t oB7 = place(768 * 2), oBc = place(1024 * 2), oB8 = place(128 * 2);
  size_t o_bse = place((size_t)B * S * 512 * 2);   // bf16 (B,S,2H)
  size_t o_proj = place((size_t)B * S * 256 * 2);  // bf16 (B,S,H)
  size_t o_U = place((size_t)4 * B * 768 * 2);     // enc: 4x(B,768) bf16
  size_t o_hfb = place((size_t)B * 512 * 4);       // f32 [h_f|h_b]
  size_t o_hbf = place((size_t)B * 512 * 2);       // bf16 mirror
  size_t o_hd = place((size_t)B * 256 * 4);        // f32 h_d
  size_t o_hdbf = place((size_t)B * 256 * 2);      // bf16 mirror

  if (ws_size < need) {
    sentinel_kernel<<<(out_size + 255) / 256, 256, 0, stream>>>(out, out_size);
    return;
  }

  char* base = (char*)d_ws;
  unsigned* dflag = (unsigned*)(base + o_flag);
  short* WT1 = (short*)(base + oWT1);
  short* WT2 = (short*)(base + oWT2);
  short* WT3 = (short*)(base + oWT3);
  short* WT4 = (short*)(base + oWT4);
  short* WT5 = (short*)(base + oWT5);
  short* WT6 = (short*)(base + oWT6);
  short* WcT = (short*)(base + oWcT);
  short* W7T = (short*)(base + oW7T);
  short* W8T = (short*)(base + oW8T);
  bf16 *B1 = (bf16*)(base + oB1), *B2 = (bf16*)(base + oB2);
  bf16 *B3 = (bf16*)(base + oB3), *B4 = (bf16*)(base + oB4);
  bf16 *B5 = (bf16*)(base + oB5), *B6 = (bf16*)(base + oB6);
  bf16 *B7 = (bf16*)(base + oB7), *Bc = (bf16*)(base + oBc);
  bf16* B8 = (bf16*)(base + oB8);
  bf16* bse = (bf16*)(base + o_bse);
  bf16* proj = (bf16*)(base + o_proj);
  bf16* U = (bf16*)(base + o_U);
  float* hfb = (float*)(base + o_hfb);
  bf16* hbf = (bf16*)(base + o_hbf);
  float* h_d = (float*)(base + o_hd);
  bf16* hdbf = (bf16*)(base + o_hdbf);
  // decoder overlay inside the U region (encoder-only lifetime):
  bf16* gi = U;                                    // (B,768)
  bf16* ghw = (bf16*)((char*)U + 3145728);         // (B,1024)
  bf16* xgc = (bf16*)((char*)U + 3145728 + 4194304);  // (B,1072)

  detect_kernel<<<1, 256, 0, stream>>>(enc_emb, dflag);

  // ---- weight prep (transposed) ----
  PrepArgs pa;
  int ns = 0;
  long long tot = 0;
  auto seg = [&](const void* s, long long soff, short* dst, int scols,
                 int dstride, int transp, long long count) {
    pa.src[ns] = s;
    pa.soff[ns] = soff;
    pa.dst[ns] = dst;
    pa.scols[ns] = scols;
    pa.dstride[ns] = dstride;
    pa.transp[ns] = transp;
    pa.prefix[ns] = tot;
    tot += count;
    ns++;
  };
  seg(enc_Wih_f, 0, WT1, 768, 304, 1, 230400);
  seg(enc_Whh_f, 0, WT2, 768, 256, 1, 196608);
  seg(enc_Wih_b, 0, WT3, 768, 304, 1, 230400);
  seg(enc_Whh_b, 0, WT4, 768, 256, 1, 196608);
  seg(enc_fcW, 0, WT5, 256, 512, 1, 131072);
  seg(attn_We, 0, WT6, 256, 512, 1, 131072);
  seg(dec_Whh, 0, WcT, 768, 256, 1, 196608);          // WcT rows 0:768
  seg(attn_Wh, 0, WcT + 768 * 256, 256, 256, 1, 65536);  // rows 768:1024
  seg(dec_Wih, 0, W7T, 768, 816, 1, 623616);
  // fcW^T with k-permutation to match xgc = [emb(300)|weighted(512)|hn(256)]
  seg(fcW, (long long)768 * 128, W8T, 128, 1072, 1, 300 * 128);
  seg(fcW, (long long)256 * 128, W8T + 300, 128, 1072, 1, 512 * 128);
  seg(fcW, 0, W8T + 812, 128, 1072, 1, 256 * 128);
  seg(enc_bih_f, 0, (short*)B1, 768, 768, 0, 768);
  seg(enc_bhh_f, 0, (short*)B2, 768, 768, 0, 768);
  seg(enc_bih_b, 0, (short*)B3, 768, 768, 0, 768);
  seg(enc_bhh_b, 0, (short*)B4, 768, 768, 0, 768);
  seg(enc_fcb, 0, (short*)B5, 256, 256, 0, 256);
  seg(attn_b, 0, (short*)B6, 256, 256, 0, 256);
  seg(dec_bih, 0, (short*)B7, 768, 768, 0, 768);
  seg(dec_bhh, 0, (short*)Bc, 768, 768, 0, 768);
  seg(nullptr, 0, (short*)(Bc + 768), 256, 256, 0, 256);  // hWh bias = 0
  seg(fcb, 0, (short*)B8, 128, 128, 0, 128);
  pa.prefix[ns] = tot;
  pa.nseg = ns;
  prep_kernel<<<(int)((tot + 255) / 256), 256, 0, stream>>>(pa, dflag);

  (void)hipMemsetAsync(hfb, 0, (size_t)B * 512 * 4, stream);
  (void)hipMemsetAsync(hbf, 0, (size_t)B * 512 * 2, stream);
  (void)hipMemsetAsync(out, 0, (size_t)B * VOUT * 4, stream);  // outputs[0]=0

  auto launch = [&](const GJob* jobs, int nj, int gx, int gy) {
    GJobs a{};
    for (int i = 0; i < nj; i++) a.j[i] = jobs[i];
    mj_gemm<<<dim3(gx, gy, nj), 256, 0, stream>>>(a, dflag);
  };
  bf16* U1 = U + (size_t)B * 768;
  bf16* U2 = U + (size_t)2 * B * 768;
  bf16* U3 = U + (size_t)3 * B * 768;

  // ---- encoder: per step one 4-job GEMM (gi_f, gh_f, gi_b, gh_b) + cell ----
  for (int s = 0; s < S; s++) {
    GJob j[4];
    j[0] = {enc_emb, src + (size_t)s * B, WT1, B1, nullptr, U, E, 304, 300, B,
            768, 1};
    j[1] = {hbf, nullptr, WT2, B2, nullptr, U1, 512, 256, 256, B, 768, 0};
    j[2] = {enc_emb, src + (size_t)(S - 1 - s) * B, WT3, B3, nullptr, U2, E,
            304, 300, B, 768, 1};
    j[3] = {hbf + 256, nullptr, WT4, B4, nullptr, U3, 512, 256, 256, B, 768,
            0};
    launch(j, 4, 12, 32);
    enc_cell<<<dim3(B, 2), 256, 0, stream>>>(U, hfb, hbf, bse, s);
  }
  // hidden = tanh([h_f,h_b]@enc_fcW+b) -> h_d(+hdbf); proj = bse@attn_We+b
  {
    GJob j[2];
    j[0] = {hbf, nullptr, WT5, B5, h_d, hdbf, 512, 512, 512, B, 256, 4};
    j[1] = {bse, nullptr, WT6, B6, nullptr, proj, 512, 512, 512, B * S, 256,
            0};
    launch(j, 2, 4, 768);
  }

  // ---- decoder ----
  auto wc_job = [&]() -> GJob {
    return {hdbf, nullptr, WcT, Bc, nullptr, ghw, 256, 256, 256, B, 1024, 0};
  };
  {
    GJob j0 = wc_job();
    launch(&j0, 1, 16, 32);
  }
  for (int t = 0; t < T - 1; t++) {
    attn_kernel<<<B, 256, 0, stream>>>(ghw, proj, bse, attn_v,
                                       trg + (size_t)t * B, dec_emb, xgc,
                                       dflag);
    GJob jw = {xgc, nullptr, W7T, B7, nullptr, gi, 1072, 816, 812, B, 768, 0};
    launch(&jw, 1, 12, 32);
    dec_cell<<<B, 256, 0, stream>>>(gi, ghw, h_d, hdbf, xgc);
    GJob jf[2];
    jf[0] = {xgc, nullptr, W8T, B8, out + (size_t)(t + 1) * B * VOUT, nullptr,
             1072, 1072, 1068, B, 128, 0};
    if (t < T - 2) {
      jf[1] = wc_job();
      launch(jf, 2, 16, 32);
    } else {
      launch(jf, 1, 2, 32);
    }
  }
}

// Round 8
// 2871.521 us; speedup vs baseline: 4.6334x; 1.0185x over previous
//
#include <hip/hip_runtime.h>
#include <hip/hip_bf16.h>

typedef __hip_bfloat16 bf16;
typedef __attribute__((ext_vector_type(8))) short short8;
typedef __attribute__((ext_vector_type(4))) float f32x4;

__device__ __forceinline__ float to_f(float x) { return x; }
__device__ __forceinline__ float to_f(bf16 x) { return __bfloat162float(x); }
__device__ __forceinline__ float ldp(const void* p, size_t i, bool f32) {
  return f32 ? ((const float*)p)[i] : __bfloat162float(((const bf16*)p)[i]);
}
__device__ __forceinline__ short f2b(float f) {
  bf16 h = __float2bfloat16(f);
  return *reinterpret_cast<short*>(&h);
}

// dtype probe: f32 data read as u16 pairs shows implausible bf16 exponents.
__global__ void detect_kernel(const void* __restrict__ probe,
                              unsigned* __restrict__ flag) {
  __shared__ int sbad;
  if (threadIdx.x == 0) sbad = 0;
  __syncthreads();
  const unsigned short* u = (const unsigned short*)probe;
  int bad = 0;
  for (int i = threadIdx.x; i < 2048; i += 256) {
    unsigned short w = u[i];
    unsigned e = (w >> 7) & 0xFFu;
    bool plaus = (w == 0) || (w == 0x8000u) || (e >= 0x60u && e <= 0x7Eu);
    if (!plaus) bad++;
  }
  atomicAdd(&sbad, bad);
  __syncthreads();
  if (threadIdx.x == 0) *flag = (sbad > 100) ? 1u : 0u;
}

// ---- weight prep: params (f32|bf16) -> bf16 ws; optional transpose ----
#define MAXSEG 24
struct PrepArgs {
  int nseg;
  const void* src[MAXSEG];
  long long soff[MAXSEG];
  short* dst[MAXSEG];
  int scols[MAXSEG];
  int dstride[MAXSEG];
  int transp[MAXSEG];
  long long prefix[MAXSEG + 1];
};
__global__ void prep_kernel(PrepArgs a, const unsigned* __restrict__ dflag) {
  const bool isf32 = (*dflag != 0u);
  long long i = (long long)blockIdx.x * 256 + threadIdx.x;
  if (i >= a.prefix[a.nseg]) return;
  int s = 0;
  while (i >= a.prefix[s + 1]) s++;
  long long loc = i - a.prefix[s];
  long long r = loc / a.scols[s], c = loc % a.scols[s];
  float v = a.src[s] ? ldp(a.src[s], (size_t)(a.soff[s] + loc), isf32) : 0.f;
  long long idx = a.transp[s] ? (c * a.dstride[s] + r) : (r * a.dstride[s] + c);
  a.dst[s][idx] = f2b(v);
}

// ---- multi-job MFMA GEMM, 128x128 tile ----
// C(M,N) = act(A @ WT^T + bias). A bf16 (lda), optionally row-gathered.
// WT bf16 [N][Kp] stride wst, zero-padded so K%32==0 needs no tail guard.
// 256 thr = 4 waves in 2x2; wave = 64x64 via 4x4 mfma_16x16x32.
// flags: 1=gather, 4=tanh.
struct GJob {
  const bf16* A;
  const int* rowidx;
  const short* WT;
  const bf16* bias;
  float* Cf;
  bf16* Ch;
  int lda, wst, K, M, N, flags;
};
struct GJobs {
  GJob j[4];
};

__global__ __launch_bounds__(256) void mj_gemm(GJobs args) {
  GJob jb = args.j[blockIdx.z];
  const int n0 = blockIdx.x * 128, m0 = blockIdx.y * 128;
  if (n0 >= jb.N || m0 >= jb.M) return;
  __shared__ short As[128][40];  // [m][k], stride 40: uniform-banked
  __shared__ short Bs[128][40];  // [n][k]
  __shared__ int rows[128];
  const int tid = threadIdx.x, lane = tid & 63, wave = tid >> 6;
  const int srow = tid >> 1, skoff = (tid & 1) * 16;
  const int wr = (wave >> 1) * 64, wc = (wave & 1) * 64;

  if (jb.flags & 1) {
    if (tid < 128) rows[tid] = jb.rowidx[m0 + tid];
    __syncthreads();
  }
  const long long arow =
      (jb.flags & 1) ? (long long)rows[srow] : (long long)(m0 + srow);
  const short* abase = (const short*)jb.A + arow * jb.lda + skoff;
  const short* bbase = jb.WT + (long long)(n0 + srow) * jb.wst + skoff;

  f32x4 acc[4][4];
#pragma unroll
  for (int i = 0; i < 4; i++)
#pragma unroll
    for (int j = 0; j < 4; j++) acc[i][j] = 0.f;

  const int K = jb.K;
  short8 a0 = *(const short8*)(abase);
  short8 a1 = *(const short8*)(abase + 8);
  short8 b0 = *(const short8*)(bbase);
  short8 b1 = *(const short8*)(bbase + 8);

  for (int k0 = 0; k0 < K; k0 += 32) {
    __syncthreads();
    *(short8*)&As[srow][skoff] = a0;
    *(short8*)&As[srow][skoff + 8] = a1;
    *(short8*)&Bs[srow][skoff] = b0;
    *(short8*)&Bs[srow][skoff + 8] = b1;
    __syncthreads();
    int kn = (k0 + 32 < K) ? k0 + 32 : k0;  // clamped prefetch (last unused)
    a0 = *(const short8*)(abase + kn);
    a1 = *(const short8*)(abase + kn + 8);
    b0 = *(const short8*)(bbase + kn);
    b1 = *(const short8*)(bbase + kn + 8);
    short8 af[4], bfr[4];
#pragma unroll
    for (int i = 0; i < 4; i++)
      af[i] = *(short8*)&As[wr + i * 16 + (lane & 15)][(lane >> 4) * 8];
#pragma unroll
    for (int j = 0; j < 4; j++)
      bfr[j] = *(short8*)&Bs[wc + j * 16 + (lane & 15)][(lane >> 4) * 8];
#pragma unroll
    for (int i = 0; i < 4; i++)
#pragma unroll
      for (int j = 0; j < 4; j++)
        acc[i][j] =
            __builtin_amdgcn_mfma_f32_16x16x32_bf16(af[i], bfr[j], acc[i][j],
                                                    0, 0, 0);
  }

  const int N = jb.N;
#pragma unroll
  for (int j = 0; j < 4; j++) {
    int col = n0 + wc + j * 16 + (lane & 15);
    float bv = jb.bias ? to_f(jb.bias[col]) : 0.f;
#pragma unroll
    for (int i = 0; i < 4; i++) {
#pragma unroll
      for (int r = 0; r < 4; r++) {
        int row = m0 + wr + i * 16 + (lane >> 4) * 4 + r;
        float v = acc[i][j][r] + bv;
        if (jb.flags & 4) v = tanhf(v);
        if (jb.Cf) jb.Cf[(long long)row * N + col] = v;
        if (jb.Ch) jb.Ch[(long long)row * N + col] = __float2bfloat16(v);
      }
    }
  }
}

// encoder dual-direction GRU cell. U = 4 segs of (B,768) bf16:
// [gi_f, gh_f, gi_b, gh_b]. dir = blockIdx.y.
__global__ __launch_bounds__(256) void enc_cell(
    const bf16* __restrict__ U, float* __restrict__ hfb,
    bf16* __restrict__ hbf, bf16* __restrict__ bse, int s) {
  int dir = blockIdx.y, b = blockIdx.x, i = threadIdx.x;
  const bf16* gi = U + ((long long)(dir * 2) * 2048 + b) * 768;
  const bf16* gh = U + ((long long)(dir * 2 + 1) * 2048 + b) * 768;
  float ir = to_f(gi[i]), iz = to_f(gi[256 + i]), in_ = to_f(gi[512 + i]);
  float hr = to_f(gh[i]), hz = to_f(gh[256 + i]), hn = to_f(gh[512 + i]);
  long long hidx = (long long)b * 512 + dir * 256 + i;
  float hv = hfb[hidx];
  float r = 1.f / (1.f + expf(-(ir + hr)));
  float z = 1.f / (1.f + expf(-(iz + hz)));
  float n = tanhf(in_ + r * hn);
  float o = (1.f - z) * n + z * hv;
  hfb[hidx] = o;
  hbf[hidx] = __float2bfloat16(o);
  int pos = dir ? (23 - s) : s;
  bse[(long long)b * (24 * 512) + pos * 512 + dir * 256 + i] =
      __float2bfloat16(o);
}

// decoder GRU cell: gi (B,768) bf16, ghw (B,1024) bf16 (first 768 = gh).
// xgc stride 1088; writes hn into cols 812:1068.
__global__ __launch_bounds__(256) void dec_cell(
    const bf16* __restrict__ gi, const bf16* __restrict__ ghw,
    float* __restrict__ h_d, bf16* __restrict__ hdbf, bf16* __restrict__ xgc) {
  int b = blockIdx.x, i = threadIdx.x;
  const bf16* gib = gi + (long long)b * 768;
  const bf16* ghb = ghw + (long long)b * 1024;
  float ir = to_f(gib[i]), iz = to_f(gib[256 + i]), in_ = to_f(gib[512 + i]);
  float hr = to_f(ghb[i]), hz = to_f(ghb[256 + i]), hn = to_f(ghb[512 + i]);
  float hv = h_d[(long long)b * 256 + i];
  float r = 1.f / (1.f + expf(-(ir + hr)));
  float z = 1.f / (1.f + expf(-(iz + hz)));
  float n = tanhf(in_ + r * hn);
  float o = (1.f - z) * n + z * hv;
  h_d[(long long)b * 256 + i] = o;
  hdbf[(long long)b * 256 + i] = __float2bfloat16(o);
  xgc[(long long)b * 1088 + 812 + i] = __float2bfloat16(o);
}

// attention + decoder embedding. hWh = ghw[:,768:1024]. embD prepped bf16
// (stride 320). Writes xgc[:,0:300]=emb, [:,300:812]=weighted (stride 1088).
__global__ __launch_bounds__(256) void attn_kernel(
    const bf16* __restrict__ ghw, const bf16* __restrict__ proj,
    const bf16* __restrict__ bse, const void* __restrict__ v,
    const int* __restrict__ trg_t, const bf16* __restrict__ embD,
    bf16* __restrict__ xgc, const unsigned* __restrict__ dflag) {
  const bool isf32 = (*dflag != 0u);
  int b = blockIdx.x, tid = threadIdx.x;
  int wave = tid >> 6, lane = tid & 63;
  __shared__ float partial[24][4];
  __shared__ float aw[24];
  float vh = to_f(ghw[(long long)b * 1024 + 768 + tid]);
  float vv = ldp(v, tid, isf32);
  const bf16* pb = proj + (long long)b * 24 * 256;
#pragma unroll 4
  for (int s = 0; s < 24; s++) {
    float e = tanhf(vh + __bfloat162float(pb[s * 256 + tid]));
    float t = vv * e;
#pragma unroll
    for (int off = 32; off > 0; off >>= 1) t += __shfl_down(t, off, 64);
    if (lane == 0) partial[s][wave] = t;
  }
  __syncthreads();
  if (tid == 0) {
    float sc[24];
    float mx = -1e30f;
    for (int s = 0; s < 24; s++) {
      float xv = partial[s][0] + partial[s][1] + partial[s][2] + partial[s][3];
      sc[s] = xv;
      mx = fmaxf(mx, xv);
    }
    float sum = 0.f;
    for (int s = 0; s < 24; s++) {
      sc[s] = expf(sc[s] - mx);
      sum += sc[s];
    }
    float inv = 1.f / sum;
    for (int s = 0; s < 24; s++) aw[s] = sc[s] * inv;
  }
  __syncthreads();
  const bf16* eb = bse + (long long)b * 24 * 512;
  float w0 = 0.f, w1 = 0.f;
#pragma unroll 4
  for (int s = 0; s < 24; s++) {
    float a = aw[s];
    w0 += a * __bfloat162float(eb[s * 512 + tid]);
    w1 += a * __bfloat162float(eb[s * 512 + 256 + tid]);
  }
  bf16* xb = xgc + (long long)b * 1088;
  xb[300 + tid] = __float2bfloat16(w0);
  xb[556 + tid] = __float2bfloat16(w1);
  long long row = trg_t[b];
  for (int e = tid; e < 300; e += 256) xb[e] = embD[row * 320 + e];
}

__global__ void sentinel_kernel(float* out, int n) {
  int i = blockIdx.x * 256 + threadIdx.x;
  if (i < n) out[i] = 123.0f;
}

extern "C" void kernel_launch(void* const* d_in, const int* in_sizes, int n_in,
                              void* d_out, int out_size, void* d_ws,
                              size_t ws_size, hipStream_t stream) {
  const int B = 2048, S = 24, T = 25, VOUT = 128;
  const int* src = (const int*)d_in[0];
  const int* trg = (const int*)d_in[1];
  const void* enc_emb = d_in[2];
  const void* enc_Wih_f = d_in[3];
  const void* enc_Whh_f = d_in[4];
  const void* enc_bih_f = d_in[5];
  const void* enc_bhh_f = d_in[6];
  const void* enc_Wih_b = d_in[7];
  const void* enc_Whh_b = d_in[8];
  const void* enc_bih_b = d_in[9];
  const void* enc_bhh_b = d_in[10];
  const void* enc_fcW = d_in[11];
  const void* enc_fcb = d_in[12];
  const void* attn_Wh = d_in[13];
  const void* attn_We = d_in[14];
  const void* attn_b = d_in[15];
  const void* attn_v = d_in[16];
  const void* dec_emb = d_in[17];
  const void* dec_Wih = d_in[18];
  const void* dec_Whh = d_in[19];
  const void* dec_bih = d_in[20];
  const void* dec_bhh = d_in[21];
  const void* fcW = d_in[22];
  const void* fcb = d_in[23];
  float* out = (float*)d_out;

  // ---- workspace layout ----
  size_t need = 0;
  auto place = [&](size_t bytes) {
    size_t off = need;
    need += (bytes + 255) & ~(size_t)255;
    return off;
  };
  size_t o_flag = place(256);
  size_t o_wstart = need;  // memset-0 region start
  size_t oEmbE = place(64 * 320 * 2);    // enc_emb bf16, k-pad 320
  size_t oEmbD = place(128 * 320 * 2);   // dec_emb bf16
  size_t oWT1 = place(768 * 320 * 2);    // enc_Wih_f^T [768][320]
  size_t oWT2 = place(768 * 256 * 2);    // enc_Whh_f^T
  size_t oWT3 = place(768 * 320 * 2);    // enc_Wih_b^T
  size_t oWT4 = place(768 * 256 * 2);    // enc_Whh_b^T
  size_t oWT5 = place(256 * 512 * 2);    // enc_fcW^T
  size_t oWT6 = place(256 * 512 * 2);    // attn_We^T
  size_t oWcT = place(1024 * 256 * 2);   // [dec_Whh | attn_Wh]^T
  size_t oW7T = place(768 * 832 * 2);    // dec_Wih^T [768][832]
  size_t oW8T = place(128 * 1088 * 2);   // fcW^T k-permuted [128][1088]
  size_t oB1 = place(768 * 2), oB2 = place(768 * 2);
  size_t oB3 = place(768 * 2), oB4 = place(768 * 2);
  size_t oB5 = place(256 * 2), oB6 = place(256 * 2);
  size_t oB7 = place(768 * 2), oBc = place(1024 * 2), oB8 = place(128 * 2);
  size_t o_wend = need;
  size_t o_bse = place((size_t)B * S * 512 * 2);
  size_t o_proj = place((size_t)B * S * 256 * 2);
  size_t o_U = place((size_t)4 * B * 768 * 2);
  size_t o_hfb = place((size_t)B * 512 * 4);
  size_t o_hbf = place((size_t)B * 512 * 2);
  size_t o_hd = place((size_t)B * 256 * 4);
  size_t o_hdbf = place((size_t)B * 256 * 2);

  if (ws_size < need) {
    sentinel_kernel<<<(out_size + 255) / 256, 256, 0, stream>>>(out, out_size);
    return;
  }

  char* base = (char*)d_ws;
  unsigned* dflag = (unsigned*)(base + o_flag);
  bf16* embE = (bf16*)(base + oEmbE);
  bf16* embD = (bf16*)(base + oEmbD);
  short* WT1 = (short*)(base + oWT1);
  short* WT2 = (short*)(base + oWT2);
  short* WT3 = (short*)(base + oWT3);
  short* WT4 = (short*)(base + oWT4);
  short* WT5 = (short*)(base + oWT5);
  short* WT6 = (short*)(base + oWT6);
  short* WcT = (short*)(base + oWcT);
  short* W7T = (short*)(base + oW7T);
  short* W8T = (short*)(base + oW8T);
  bf16 *B1 = (bf16*)(base + oB1), *B2 = (bf16*)(base + oB2);
  bf16 *B3 = (bf16*)(base + oB3), *B4 = (bf16*)(base + oB4);
  bf16 *B5 = (bf16*)(base + oB5), *B6 = (bf16*)(base + oB6);
  bf16 *B7 = (bf16*)(base + oB7), *Bc = (bf16*)(base + oBc);
  bf16* B8 = (bf16*)(base + oB8);
  bf16* bse = (bf16*)(base + o_bse);
  bf16* proj = (bf16*)(base + o_proj);
  bf16* U = (bf16*)(base + o_U);
  float* hfb = (float*)(base + o_hfb);
  bf16* hbf = (bf16*)(base + o_hbf);
  float* h_d = (float*)(base + o_hd);
  bf16* hdbf = (bf16*)(base + o_hdbf);
  // decoder overlay inside U (encoder-only lifetime): gi, ghw, xgc
  bf16* gi = U;                                         // (B,768)
  bf16* ghw = U + (size_t)B * 768;                      // (B,1024)
  bf16* xgc = U + (size_t)B * 768 + (size_t)B * 1024;   // (B,1088)

  detect_kernel<<<1, 256, 0, stream>>>(enc_emb, dflag);
  (void)hipMemsetAsync(base + o_wstart, 0, o_wend - o_wstart, stream);

  // ---- weight prep ----
  PrepArgs pa;
  int ns = 0;
  long long tot = 0;
  auto seg = [&](const void* s, long long soff, short* dst, int scols,
                 int dstride, int transp, long long count) {
    pa.src[ns] = s;
    pa.soff[ns] = soff;
    pa.dst[ns] = dst;
    pa.scols[ns] = scols;
    pa.dstride[ns] = dstride;
    pa.transp[ns] = transp;
    pa.prefix[ns] = tot;
    tot += count;
    ns++;
  };
  seg(enc_emb, 0, (short*)embE, 300, 320, 0, 64 * 300);
  seg(dec_emb, 0, (short*)embD, 300, 320, 0, 128 * 300);
  seg(enc_Wih_f, 0, WT1, 768, 320, 1, 230400);
  seg(enc_Whh_f, 0, WT2, 768, 256, 1, 196608);
  seg(enc_Wih_b, 0, WT3, 768, 320, 1, 230400);
  seg(enc_Whh_b, 0, WT4, 768, 256, 1, 196608);
  seg(enc_fcW, 0, WT5, 256, 512, 1, 131072);
  seg(attn_We, 0, WT6, 256, 512, 1, 131072);
  seg(dec_Whh, 0, WcT, 768, 256, 1, 196608);
  seg(attn_Wh, 0, WcT + 768 * 256, 256, 256, 1, 65536);
  seg(dec_Wih, 0, W7T, 768, 832, 1, 623616);
  // fcW^T k-permuted to xgc = [emb(0:300)|weighted(300:812)|hn(812:1068)]
  seg(fcW, (long long)768 * 128, W8T, 128, 1088, 1, 300 * 128);
  seg(fcW, (long long)256 * 128, W8T + 300, 128, 1088, 1, 512 * 128);
  seg(fcW, 0, W8T + 812, 128, 1088, 1, 256 * 128);
  seg(enc_bih_f, 0, (short*)B1, 768, 768, 0, 768);
  seg(enc_bhh_f, 0, (short*)B2, 768, 768, 0, 768);
  seg(enc_bih_b, 0, (short*)B3, 768, 768, 0, 768);
  seg(enc_bhh_b, 0, (short*)B4, 768, 768, 0, 768);
  seg(enc_fcb, 0, (short*)B5, 256, 256, 0, 256);
  seg(attn_b, 0, (short*)B6, 256, 256, 0, 256);
  seg(dec_bih, 0, (short*)B7, 768, 768, 0, 768);
  seg(dec_bhh, 0, (short*)Bc, 768, 768, 0, 768);  // Bc[768:1024] stays 0
  seg(fcb, 0, (short*)B8, 128, 128, 0, 128);
  pa.prefix[ns] = tot;
  pa.nseg = ns;
  prep_kernel<<<(int)((tot + 255) / 256), 256, 0, stream>>>(pa, dflag);

  (void)hipMemsetAsync(hfb, 0, (size_t)B * 512 * 4, stream);
  (void)hipMemsetAsync(hbf, 0, (size_t)B * 512 * 2, stream);
  (void)hipMemsetAsync(out, 0, (size_t)B * VOUT * 4, stream);  // outputs[0]=0

  auto launch = [&](const GJob* jobs, int nj, int gx, int gy) {
    GJobs a{};
    for (int i = 0; i < nj; i++) a.j[i] = jobs[i];
    mj_gemm<<<dim3(gx, gy, nj), 256, 0, stream>>>(a);
  };
  bf16* U1 = U + (size_t)B * 768;
  bf16* U2 = U + (size_t)2 * B * 768;
  bf16* U3 = U + (size_t)3 * B * 768;

  // ---- encoder: per step one 4-job GEMM + cell ----
  for (int s = 0; s < S; s++) {
    GJob j[4];
    j[0] = {embE, src + (size_t)s * B, WT1, B1, nullptr, U, 320, 320, 320, B,
            768, 1};
    j[1] = {hbf, nullptr, WT2, B2, nullptr, U1, 512, 256, 256, B, 768, 0};
    j[2] = {embE, src + (size_t)(S - 1 - s) * B, WT3, B3, nullptr, U2, 320,
            320, 320, B, 768, 1};
    j[3] = {hbf + 256, nullptr, WT4, B4, nullptr, U3, 512, 256, 256, B, 768,
            0};
    launch(j, 4, 6, 16);
    enc_cell<<<dim3(B, 2), 256, 0, stream>>>(U, hfb, hbf, bse, s);
  }
  // hidden = tanh([h_f,h_b]@enc_fcW+b) -> h_d/hdbf; proj = bse@attn_We+attn_b
  {
    GJob j[2];
    j[0] = {hbf, nullptr, WT5, B5, h_d, hdbf, 512, 512, 512, B, 256, 4};
    j[1] = {bse, nullptr, WT6, B6, nullptr, proj, 512, 512, 512, B * S, 256,
            0};
    launch(j, 2, 2, 384);
  }

  // ---- decoder ----
  auto wc_job = [&]() -> GJob {
    return {hdbf, nullptr, WcT, Bc, nullptr, ghw, 256, 256, 256, B, 1024, 0};
  };
  {
    GJob j0 = wc_job();
    launch(&j0, 1, 8, 16);
  }
  for (int t = 0; t < T - 1; t++) {
    attn_kernel<<<B, 256, 0, stream>>>(ghw, proj, bse, attn_v,
                                       trg + (size_t)t * B, embD, xgc, dflag);
    GJob jw = {xgc, nullptr, W7T, B7, nullptr, gi, 1088, 832, 832, B, 768, 0};
    launch(&jw, 1, 6, 16);
    dec_cell<<<B, 256, 0, stream>>>(gi, ghw, h_d, hdbf, xgc);
    GJob jf[2];
    jf[0] = {xgc, nullptr, W8T, B8, out + (size_t)(t + 1) * B * VOUT, nullptr,
             1088, 1088, 1088, B, 128, 0};
    if (t < T - 2) {
      jf[1] = wc_job();
      launch(jf, 2, 8, 16);
    } else {
      launch(jf, 1, 1, 16);
    }
  }
}